// Round 4
// baseline (3307.978 us; speedup 1.0000x reference)
//
#include <hip/hip_runtime.h>

// T=512, B=64, D=H=1024, gates=4096
#define TT 512
#define NB 64
#define DD 1024
#define NG 4096

typedef __attribute__((ext_vector_type(8))) __bf16 bf16x8;
typedef __attribute__((ext_vector_type(4))) float f32x4;

// workspace layout (bytes)
#define WC_OFF   0ul                       // bf16 [4096][2048]             = 16,777,216
#define HB2_OFF  16777216ul                // u64  [2][256 tiles][128] tagged = 524,288
#define FLG_OFF  (HB2_OFF + 524288ul)      // u32  [4][128] hint pairs      = 2,048
#define BIAS_OFF (FLG_OFF + 2048ul)        // f32  [4096]                   = 16,384
#define XBF_OFF  (BIAS_OFF + 16384ul)      // bf16 x mirror                 = 67,108,864
#define WS_FULL  (XBF_OFF + 67108864ul)

__device__ __forceinline__ unsigned short f2bf(float f) {
  unsigned int u = __float_as_uint(f);
  u += 0x7fffu + ((u >> 16) & 1u);   // round-to-nearest-even
  return (unsigned short)(u >> 16);
}

__global__ void prep_kernel(const float* __restrict__ x, const float* __restrict__ h0,
                            const float* __restrict__ w_ih, const float* __restrict__ b_ih,
                            const float* __restrict__ w_hh, const float* __restrict__ b_hh,
                            unsigned char* __restrict__ ws, int use_xbf) {
  unsigned short* Wc  = (unsigned short*)(ws + WC_OFF);
  unsigned long long* hb2 = (unsigned long long*)(ws + HB2_OFF);
  unsigned int* flg   = (unsigned int*)(ws + FLG_OFF);
  float* bias         = (float*)(ws + BIAS_OFF);
  unsigned short* xbf = (unsigned short*)(ws + XBF_OFF);
  long tid = (long)blockIdx.x * blockDim.x + threadIdx.x;
  long stride = (long)gridDim.x * blockDim.x;
  // W_cat[r][k] = k<1024 ? w_ih[r][k] : w_hh[r][k-1024]  (bf16)
  for (long i = tid; i < (long)NG * 2048; i += stride) {
    int r = (int)(i >> 11), k = (int)(i & 2047);
    float v = (k < 1024) ? w_ih[(long)r * 1024 + k] : w_hh[(long)r * 1024 + (k - 1024)];
    Wc[i] = f2bf(v);
  }
  for (long i = tid; i < NG; i += stride) bias[i] = b_ih[i] + b_hh[i];
  // h_{-1} -> tile-blocked TAGGED buf1 (tag 0); buf0 zeroed (tag 0 != expected 1)
  // tile T = (row>>4)*64 + colpair>>3 ; u64 idx = T*128 + (row&15)*8 + (colpair&7)
  for (long i = tid; i < (long)NB * 512; i += stride) {
    int row = (int)(i >> 9), cp = (int)(i & 511);
    const float* hp = h0 + (long)row * 1024 + 2 * cp;
    long idx = ((long)(row >> 4) * 64 + (cp >> 3)) * 128 + (row & 15) * 8 + (cp & 7);
    hb2[32768 + idx] = (unsigned long long)f2bf(hp[0]) | ((unsigned long long)f2bf(hp[1]) << 16);
    hb2[idx] = 0ull;
  }
  for (long i = tid; i < 512; i += stride) flg[i] = 0;
  if (use_xbf) {
    for (long i = tid; i < (long)TT * NB * DD; i += stride) xbf[i] = f2bf(x[i]);
  }
}

#define MFMA16 __builtin_amdgcn_mfma_f32_16x16x32_bf16

// 256 wgs (1/CU): bg = blockIdx>>6 (16 batch rows), cg = blockIdx&63 (16 h-cols).
// 8 waves, each owns K-cols [wv*128, wv*128+128) of x AND of h (K=2048 fused).
// Weights register-resident. h-exchange: HINT-GATED TAGGED PUBLISH.
//   producer: store 1 tagged u64 per lane {2 bf16 | tag=t+1}, then hint flag —
//             NO vmcnt drain (value-validation replaces store ordering).
//   consumer: spin on cheap hint u64 (64 B/wave/iter); then load 16 tagged data
//             words and verify tags==t; retry (rare) only on hint/data skew.
// Overwrite safety: 2-buffer parity + whole-bg gating => reuse distance 2. A
// producer writes buf[p] at step t+1 only after ALL 64 wgs' hints >= t+1, which
// requires every wg's step-t barrier, which follows consumption (MFMA-completed)
// of the h loads from buf[p] at step t. Tags seen in a buffer are {t-2, t} only.
__launch_bounds__(512, 2)
__global__ void lstm_kernel(const float* __restrict__ x, const float* __restrict__ c0,
                            float* __restrict__ out, unsigned char* __restrict__ ws,
                            int use_xbf) {
  __shared__ __align__(16) float red[2][8][16][68];  // 69,632 B double-buffered partials
  __shared__ float bias_l[64];

  const unsigned short* Wc  = (const unsigned short*)(ws + WC_OFF);
  unsigned long long* hbq   = (unsigned long long*)(ws + HB2_OFF);  // [2][32768] u64
  const unsigned long long* flgq = (const unsigned long long*)(ws + FLG_OFF);
  unsigned int* flg         = (unsigned int*)(ws + FLG_OFF);
  const float* bias         = (const float*)(ws + BIAS_OFF);
  const unsigned short* xbf = (const unsigned short*)(ws + XBF_OFF);

  const int tid = threadIdx.x;
  const int bg = blockIdx.x >> 6;
  const int cg = blockIdx.x & 63;
  const int m0 = bg << 4;           // batch base
  const int j0 = cg << 4;           // h-col base
  const int wv = tid >> 6;          // wave 0..7
  const int lane = tid & 63;
  const int ln = lane & 15;
  const int lq = lane >> 4;

  // ---- preload weights (once): wx = x-half K-chunk, wh = h-half ----
  bf16x8 wx[16], wh[16];
  {
    const int kx = wv * 128 + lq * 8;
#pragma unroll
    for (int g = 0; g < 4; ++g) {   // g = gate
      const unsigned short* wp = Wc + (long)(g * 1024 + j0 + ln) * 2048 + kx;
#pragma unroll
      for (int ks = 0; ks < 4; ++ks) {
        wx[g * 4 + ks] = *reinterpret_cast<const bf16x8*>(wp + ks * 32);
        wh[g * 4 + ks] = *reinterpret_cast<const bf16x8*>(wp + 1024 + ks * 32);
      }
    }
  }
  if (tid < 64) bias_l[tid] = bias[(tid >> 4) * 1024 + j0 + (tid & 15)];

  // ---- reducer role (waves 0,1): 2 cells/lane, cell state in registers ----
  const int rrow = ((wv & 1) << 3) + (lane >> 3);   // wave0: rows 0-7, wave1: 8-15
  const int jc   = lane & 7;                        // col pair -> cols 2jc, 2jc+1
  float cr0 = 0.f, cr1 = 0.f;
  if (wv < 2) {
    const float2 cv = *(const float2*)(c0 + (long)(m0 + rrow) * DD + j0 + 2 * jc);
    cr0 = cv.x; cr1 = cv.y;
  }

  // ---- x fragment prefetch (registers, 1 step ahead) ----
  const long xbase = (long)(m0 + ln) * DD + wv * 128 + lq * 8;
  uint4 xcur[4];
  auto load_x = [&](int tt) {
    if (use_xbf) {
      const unsigned short* xp = xbf + (long)tt * (NB * DD) + xbase;
#pragma unroll
      for (int ks = 0; ks < 4; ++ks)
        xcur[ks] = *reinterpret_cast<const uint4*>(xp + ks * 32);
    } else {
      const float* xp = x + (long)tt * (NB * DD) + xbase;
#pragma unroll
      for (int ks = 0; ks < 4; ++ks) {
        float4 f0 = *reinterpret_cast<const float4*>(xp + ks * 32);
        float4 f1 = *reinterpret_cast<const float4*>(xp + ks * 32 + 4);
        uint4 pk;
        pk.x = (unsigned)f2bf(f0.x) | ((unsigned)f2bf(f0.y) << 16);
        pk.y = (unsigned)f2bf(f0.z) | ((unsigned)f2bf(f0.w) << 16);
        pk.z = (unsigned)f2bf(f1.x) | ((unsigned)f2bf(f1.y) << 16);
        pk.w = (unsigned)f2bf(f1.z) | ((unsigned)f2bf(f1.w) << 16);
        xcur[ks] = pk;
      }
    }
  };
  load_x(0);

  // consumer h addressing (u64 units): frag ks -> tile wv*8+2ks+(lq>>1), row ln,
  // col-pairs (lq&1)*4 + 0..3
  int qoff[4];
#pragma unroll
  for (int ks = 0; ks < 4; ++ks)
    qoff[ks] = (bg * 64 + wv * 8 + 2 * ks + (lq >> 1)) * 128 + ln * 8 + (lq & 1) * 4;
  // hint poll address (u64 covering both reducer-wave hints of one producer)
  const int foff = bg * 64 + wv * 8 + (lane & 7);

#pragma unroll 1
  for (int t = 0; t < TT; ++t) {
    const int rb = t & 1;

    // ---- cheap hint spin (advisory) ----
    if (t > 0) {
      const unsigned tgt = (unsigned)t;
      while (true) {
        unsigned long long v = __hip_atomic_load(flgq + foff, __ATOMIC_RELAXED,
                                                 __HIP_MEMORY_SCOPE_AGENT);
        bool ok = ((unsigned)v >= tgt) && ((unsigned)(v >> 32) >= tgt);
        if (__all(ok)) break;
        __builtin_amdgcn_s_sleep(1);
      }
    }

    // ---- tagged h load + verify (ground truth; retry on rare skew) ----
    const unsigned long long* hp = hbq + (((t + 1) & 1) << 15);
    const unsigned tgt = (unsigned)t;
    unsigned long long q[16];
    while (true) {
#pragma unroll
      for (int ks = 0; ks < 4; ++ks)
#pragma unroll
        for (int u = 0; u < 4; ++u)
          q[ks * 4 + u] = __hip_atomic_load(hp + qoff[ks] + u,
                                            __ATOMIC_RELAXED, __HIP_MEMORY_SCOPE_AGENT);
      bool ok = true;
#pragma unroll
      for (int i = 0; i < 16; ++i) ok &= ((unsigned)(q[i] >> 32) == tgt);
      if (__all(ok)) break;
      __builtin_amdgcn_s_sleep(0);
      asm volatile("" ::: "memory");
    }

    // ---- x MFMAs (prefetched regs) ----
    f32x4 a0 = {0.f, 0.f, 0.f, 0.f}, a1 = a0, a2 = a0, a3 = a0;
#pragma unroll
    for (int ks = 0; ks < 4; ++ks) {
      bf16x8 af = __builtin_bit_cast(bf16x8, xcur[ks]);
      a0 = MFMA16(af, wx[ks],      a0, 0, 0, 0);
      a1 = MFMA16(af, wx[4 + ks],  a1, 0, 0, 0);
      a2 = MFMA16(af, wx[8 + ks],  a2, 0, 0, 0);
      a3 = MFMA16(af, wx[12 + ks], a3, 0, 0, 0);
    }
    // non-reducer waves prefetch x for t+1 (rides across the lgkm-only barrier)
    if (wv >= 2 && t + 1 < TT) load_x(t + 1);

    // ---- h MFMAs (unpack low u32 of each tagged word) ----
#pragma unroll
    for (int ks = 0; ks < 4; ++ks) {
      uint4 pk;
      pk.x = (unsigned)q[ks * 4 + 0];
      pk.y = (unsigned)q[ks * 4 + 1];
      pk.z = (unsigned)q[ks * 4 + 2];
      pk.w = (unsigned)q[ks * 4 + 3];
      bf16x8 hf = __builtin_bit_cast(bf16x8, pk);
      a0 = MFMA16(hf, wh[ks],      a0, 0, 0, 0);
      a1 = MFMA16(hf, wh[4 + ks],  a1, 0, 0, 0);
      a2 = MFMA16(hf, wh[8 + ks],  a2, 0, 0, 0);
      a3 = MFMA16(hf, wh[12 + ks], a3, 0, 0, 0);
    }

    // ---- write partials (D layout: col=lane&15, row=(lane>>4)*4+r) ----
#pragma unroll
    for (int r = 0; r < 4; ++r) {
      float* rp = &red[rb][wv][lq * 4 + r][ln];
      rp[0] = a0[r]; rp[16] = a1[r]; rp[32] = a2[r]; rp[48] = a3[r];
    }

    // lgkm-only barrier: LDS partials visible; vm loads/stores stay in flight
    asm volatile("s_waitcnt lgkmcnt(0)" ::: "memory");
    __builtin_amdgcn_s_barrier();
    __builtin_amdgcn_sched_barrier(0);

    // ---- reduce + cell update + tagged publish (waves 0,1) ----
    if (wv < 2) {
      __builtin_amdgcn_s_setprio(1);
      float s00 = bias_l[2 * jc],      s01 = bias_l[2 * jc + 1];
      float s10 = bias_l[16 + 2 * jc], s11 = bias_l[16 + 2 * jc + 1];
      float s20 = bias_l[32 + 2 * jc], s21 = bias_l[32 + 2 * jc + 1];
      float s30 = bias_l[48 + 2 * jc], s31 = bias_l[48 + 2 * jc + 1];
#pragma unroll
      for (int w = 0; w < 8; ++w) {
        const float* rp = &red[rb][w][rrow][2 * jc];
        float2 v0 = *(const float2*)(rp);
        float2 v1 = *(const float2*)(rp + 16);
        float2 v2 = *(const float2*)(rp + 32);
        float2 v3 = *(const float2*)(rp + 48);
        s00 += v0.x; s01 += v0.y;
        s10 += v1.x; s11 += v1.y;
        s20 += v2.x; s21 += v2.y;
        s30 += v3.x; s31 += v3.y;
      }
      // x prefetch in flight under the transcendental chain
      if (t + 1 < TT) load_x(t + 1);
      float ig0 = 1.f / (1.f + __expf(-s00)), ig1 = 1.f / (1.f + __expf(-s01));
      float fg0 = 1.f / (1.f + __expf(-s10)), fg1 = 1.f / (1.f + __expf(-s11));
      float gg0 = 1.f - 2.f / (__expf(2.f * s20) + 1.f);
      float gg1 = 1.f - 2.f / (__expf(2.f * s21) + 1.f);
      float og0 = 1.f / (1.f + __expf(-s30)), og1 = 1.f / (1.f + __expf(-s31));
      float cn0 = fg0 * cr0 + ig0 * gg0;
      float cn1 = fg1 * cr1 + ig1 * gg1;
      cr0 = cn0; cr1 = cn1;
      float hv0 = og0 * (1.f - 2.f / (__expf(2.f * cn0) + 1.f));
      float hv1 = og1 * (1.f - 2.f / (__expf(2.f * cn1) + 1.f));

      // tagged publish (NO drain), then hint, then out
      unsigned long long pw = (unsigned long long)f2bf(hv0)
        | ((unsigned long long)f2bf(hv1) << 16)
        | ((unsigned long long)(unsigned)(t + 1) << 32);
      __hip_atomic_store(hbq + ((long)rb << 15) + (bg * 64 + cg) * 128 + rrow * 8 + jc, pw,
                         __ATOMIC_RELAXED, __HIP_MEMORY_SCOPE_AGENT);
      if (lane == 0)
        __hip_atomic_store(flg + bg * 128 + 2 * cg + wv, (unsigned)(t + 1),
                           __ATOMIC_RELAXED, __HIP_MEMORY_SCOPE_AGENT);

      const long ho = (long)(m0 + rrow) * 1024 + j0 + 2 * jc;
      *(float2*)(out + (long)t * 65536 + ho) = make_float2(hv0, hv1);
      if (t == TT - 1) {
        *(float2*)(out + (long)TT * 65536 + ho) = make_float2(hv0, hv1);
        *(float2*)(out + (long)TT * 65536 + 65536 + ho) = make_float2(cn0, cn1);
      }
      __builtin_amdgcn_s_setprio(0);
    }
  }
}

extern "C" void kernel_launch(void* const* d_in, const int* in_sizes, int n_in,
                              void* d_out, int out_size, void* d_ws, size_t ws_size,
                              hipStream_t stream) {
  const float* x    = (const float*)d_in[0];
  const float* h0   = (const float*)d_in[1];
  const float* c0   = (const float*)d_in[2];
  const float* w_ih = (const float*)d_in[3];
  const float* b_ih = (const float*)d_in[4];
  const float* w_hh = (const float*)d_in[5];
  const float* b_hh = (const float*)d_in[6];
  float* out = (float*)d_out;
  unsigned char* ws = (unsigned char*)d_ws;
  int use_xbf = (ws_size >= WS_FULL) ? 1 : 0;

  hipLaunchKernelGGL(prep_kernel, dim3(2048), dim3(256), 0, stream,
                     x, h0, w_ih, b_ih, w_hh, b_hh, ws, use_xbf);

  void* args[] = { (void*)&x, (void*)&c0, (void*)&out, (void*)&ws, (void*)&use_xbf };
  hipLaunchCooperativeKernel(reinterpret_cast<void*>(lstm_kernel),
                             dim3(256), dim3(512), args, 0, stream);
}